// Round 1
// baseline (3337.429 us; speedup 1.0000x reference)
//
#include <hip/hip_runtime.h>

// GRU decoder: B*N=65536 independent rows, H=256, T=12, D_OUT=64.
// One block = 64 rows, full 12-step recurrence in-kernel, h state in LDS (f16).
// All matmuls on f16 MFMA (32x32x16), fp32 accumulate + fp32 nonlinearities.

#define NROWS   65536
#define HDIM    256
#define GDIM    512
#define TSTEPS  12
#define DOUT    64
#define MT      64          // rows per block

typedef _Float16 f16x8 __attribute__((ext_vector_type(8)));
typedef _Float16 f16x4 __attribute__((ext_vector_type(4)));
typedef float    f32x16 __attribute__((ext_vector_type(16)));

#define WG_ELEMS (GDIM*HDIM)              // folded gate weights [512][256]
#define WO_ELEMS (HDIM*GDIM)              // out weights        [256][512]
#define WP_ELEMS (DOUT*HDIM)              // proj weights       [64][256]
#define WO_OFF   WG_ELEMS
#define WP_OFF   (WG_ELEMS + WO_ELEMS)
#define PREP_TOTAL (WG_ELEMS + WO_ELEMS + WP_ELEMS)

// ---- prep: fold gate_w (input==h -> Wg[j,k] = gw[j,k]+gw[j,k+256]), cast all to f16 ----
__global__ void prep_weights(const float* __restrict__ gw,
                             const float* __restrict__ ow,
                             const float* __restrict__ pw,
                             _Float16* __restrict__ ws)
{
    int idx = blockIdx.x * 256 + threadIdx.x;
    if (idx < WG_ELEMS) {
        int j = idx >> 8, k = idx & 255;
        ws[idx] = (_Float16)(gw[j*GDIM + k] + gw[j*GDIM + HDIM + k]);
    } else if (idx < WG_ELEMS + WO_ELEMS) {
        ws[idx] = (_Float16)ow[idx - WG_ELEMS];
    } else if (idx < PREP_TOTAL) {
        ws[idx] = (_Float16)pw[idx - (WG_ELEMS + WO_ELEMS)];
    }
}

#define LDS_H    0
#define LDS_RH   32768
#define LDS_BYTES 65536

// XOR swizzle: rows are 512B; spread 8 consecutive rows across 8 distinct 16B slots
__device__ __forceinline__ int swz(int row, int b) {
    return row*512 + (b ^ ((row & 7) << 4));
}
__device__ __forceinline__ float sigm(float x)   { return 1.0f / (1.0f + __expf(-x)); }
__device__ __forceinline__ float tanhf_(float x) { return 1.0f - 2.0f / (1.0f + __expf(2.0f*x)); }

__global__ __launch_bounds__(512, 2)
void gru_dec(const float* __restrict__ h_in,
             const _Float16* __restrict__ W,
             const float* __restrict__ gate_b,
             const float* __restrict__ out_b,
             const float* __restrict__ proj_b,
             float* __restrict__ out)
{
    __shared__ __align__(16) unsigned char lds[LDS_BYTES];
    const int tid  = threadIdx.x;
    const int lane = tid & 63;
    const int w    = tid >> 6;            // wave 0..7
    const int row0 = blockIdx.x * MT;

    // ---- stage h tile: fp32 global -> f16 LDS (swizzled), coalesced ----
    {
        const int r   = tid >> 3;         // 0..63
        const int seg = tid & 7;
        const float* src = h_in + (size_t)(row0 + r) * HDIM;
        #pragma unroll
        for (int i = 0; i < 8; ++i) {
            const int c4 = (seg + 8*i) * 4;
            float4 v = *(const float4*)(src + c4);
            f16x4 p;
            p[0] = (_Float16)v.x; p[1] = (_Float16)v.y;
            p[2] = (_Float16)v.z; p[3] = (_Float16)v.w;
            *(f16x4*)&lds[LDS_H + swz(r, c4*2)] = p;
        }
    }
    __syncthreads();

    const int mw = w >> 2;                // m-tile (32 rows): 0..1
    const int cw = w & 3;                 // 64-col chunk:     0..3
    const int bn = lane & 31;
    const int kg = lane >> 5;             // k-half of fragment
    const int arow = mw*32 + bn;          // A-fragment row

    // biases: per-lane scalars from global (L1-cached, tiny)
    const float bgr0 = gate_b[cw*64 + bn];
    const float bgr1 = gate_b[cw*64 + 32 + bn];
    const float bgz0 = gate_b[HDIM + cw*64 + bn];
    const float bgz1 = gate_b[HDIM + cw*64 + 32 + bn];
    const float bo0  = out_b[cw*64 + bn];
    const float bo1  = out_b[cw*64 + 32 + bn];
    const float bp   = (w < 4) ? proj_b[(w & 1)*32 + bn] : 0.0f;

    // B-fragment row pointers (W rows are contiguous K; lane reads 16B chunks)
    const _Float16* wg_r0 = W + (cw*64      + bn)*HDIM + kg*8;
    const _Float16* wg_r1 = W + (cw*64 + 32 + bn)*HDIM + kg*8;
    const _Float16* wg_z0 = W + (HDIM + cw*64      + bn)*HDIM + kg*8;
    const _Float16* wg_z1 = W + (HDIM + cw*64 + 32 + bn)*HDIM + kg*8;
    const _Float16* wo_0  = W + WO_OFF + (cw*64      + bn)*GDIM + kg*8;
    const _Float16* wo_1  = W + WO_OFF + (cw*64 + 32 + bn)*GDIM + kg*8;
    const _Float16* wp_p  = W + WP_OFF + ((w & 1)*32 + bn)*HDIM + kg*8;

    float z_vals[32];

    for (int t = 0; t < TSTEPS; ++t) {
        // ---- fused GEMM1 (gates, 4 tiles) + GEMM2 part1 (h @ out_w1^T, 2 tiles) ----
        f32x16 g0 = {}, g1 = {}, g2 = {}, g3 = {}, o0 = {}, o1 = {};
        #pragma unroll
        for (int ks = 0; ks < 16; ++ks) {
            f16x8 a  = *(const f16x8*)&lds[LDS_H + swz(arow, ks*32 + kg*16)];
            f16x8 b0 = *(const f16x8*)(wg_r0 + ks*16);
            f16x8 b1 = *(const f16x8*)(wg_r1 + ks*16);
            f16x8 b2 = *(const f16x8*)(wg_z0 + ks*16);
            f16x8 b3 = *(const f16x8*)(wg_z1 + ks*16);
            f16x8 c0 = *(const f16x8*)(wo_0 + ks*16);
            f16x8 c1 = *(const f16x8*)(wo_1 + ks*16);
            g0 = __builtin_amdgcn_mfma_f32_32x32x16_f16(a, b0, g0, 0, 0, 0);
            g1 = __builtin_amdgcn_mfma_f32_32x32x16_f16(a, b1, g1, 0, 0, 0);
            g2 = __builtin_amdgcn_mfma_f32_32x32x16_f16(a, b2, g2, 0, 0, 0);
            g3 = __builtin_amdgcn_mfma_f32_32x32x16_f16(a, b3, g3, 0, 0, 0);
            o0 = __builtin_amdgcn_mfma_f32_32x32x16_f16(a, c0, o0, 0, 0, 0);
            o1 = __builtin_amdgcn_mfma_f32_32x32x16_f16(a, c1, o1, 0, 0, 0);
        }

        // ---- r = sigmoid(gates_r); write rh = r*h (C-frag layout, scattered u16) ----
        #pragma unroll
        for (int e = 0; e < 16; ++e) {
            const int row = mw*32 + (e & 3) + 8*(e >> 2) + 4*kg;
            {
                const int col = cw*64 + bn;
                float r  = sigm(g0[e] + bgr0);
                float hc = (float)(*(const _Float16*)&lds[LDS_H + swz(row, col*2)]);
                *(_Float16*)&lds[LDS_RH + swz(row, col*2)] = (_Float16)(r * hc);
            }
            {
                const int col = cw*64 + 32 + bn;
                float r  = sigm(g1[e] + bgr1);
                float hc = (float)(*(const _Float16*)&lds[LDS_H + swz(row, col*2)]);
                *(_Float16*)&lds[LDS_RH + swz(row, col*2)] = (_Float16)(r * hc);
            }
            z_vals[e]      = sigm(g2[e] + bgz0);
            z_vals[16 + e] = sigm(g3[e] + bgz1);
        }
        __syncthreads();   // rh visible to all waves

        // ---- GEMM2 part2: o += rh @ out_w2^T ----
        #pragma unroll
        for (int ks = 0; ks < 16; ++ks) {
            f16x8 a  = *(const f16x8*)&lds[LDS_RH + swz(arow, ks*32 + kg*16)];
            f16x8 b0 = *(const f16x8*)(wo_0 + HDIM + ks*16);
            f16x8 b1 = *(const f16x8*)(wo_1 + HDIM + ks*16);
            o0 = __builtin_amdgcn_mfma_f32_32x32x16_f16(a, b0, o0, 0, 0, 0);
            o1 = __builtin_amdgcn_mfma_f32_32x32x16_f16(a, b1, o1, 0, 0, 0);
        }

        // ---- state update: hn = z*h + (1-z)*tanh(o + bo)  (own (row,col), no race) ----
        #pragma unroll
        for (int e = 0; e < 16; ++e) {
            const int row = mw*32 + (e & 3) + 8*(e >> 2) + 4*kg;
            {
                const int col = cw*64 + bn;
                float hnew = tanhf_(o0[e] + bo0);
                float hc = (float)(*(const _Float16*)&lds[LDS_H + swz(row, col*2)]);
                float z  = z_vals[e];
                *(_Float16*)&lds[LDS_H + swz(row, col*2)] = (_Float16)(z*hc + (1.0f - z)*hnew);
            }
            {
                const int col = cw*64 + 32 + bn;
                float hnew = tanhf_(o1[e] + bo1);
                float hc = (float)(*(const _Float16*)&lds[LDS_H + swz(row, col*2)]);
                float z  = z_vals[16 + e];
                *(_Float16*)&lds[LDS_H + swz(row, col*2)] = (_Float16)(z*hc + (1.0f - z)*hnew);
            }
        }
        __syncthreads();   // updated h visible

        // ---- GEMM3: out_t = hn @ proj_w^T + pb (waves 0..3; 4 output tiles) ----
        if (w < 4) {
            const int arow3 = (w >> 1)*32 + bn;
            f32x16 p = {};
            #pragma unroll
            for (int ks = 0; ks < 16; ++ks) {
                f16x8 a = *(const f16x8*)&lds[LDS_H + swz(arow3, ks*32 + kg*16)];
                f16x8 b = *(const f16x8*)(wp_p + ks*16);
                p = __builtin_amdgcn_mfma_f32_32x32x16_f16(a, b, p, 0, 0, 0);
            }
            #pragma unroll
            for (int e = 0; e < 16; ++e) {
                const int row = (w >> 1)*32 + (e & 3) + 8*(e >> 2) + 4*kg;
                out[((size_t)(row0 + row)*TSTEPS + t)*DOUT + (w & 1)*32 + bn] = p[e] + bp;
            }
        }
    }
}

extern "C" void kernel_launch(void* const* d_in, const int* in_sizes, int n_in,
                              void* d_out, int out_size, void* d_ws, size_t ws_size,
                              hipStream_t stream) {
    // inputs: 0:x(=12) 1:h 2:gate_w 3:gate_b 4:out_w 5:out_b 6:proj_w 7:proj_b
    const float* h  = (const float*)d_in[1];
    const float* gw = (const float*)d_in[2];
    const float* gb = (const float*)d_in[3];
    const float* ow = (const float*)d_in[4];
    const float* ob = (const float*)d_in[5];
    const float* pw = (const float*)d_in[6];
    const float* pb = (const float*)d_in[7];
    if (ws_size < (size_t)PREP_TOTAL * sizeof(_Float16)) return;
    _Float16* ws = (_Float16*)d_ws;

    hipLaunchKernelGGL(prep_weights, dim3((PREP_TOTAL + 255)/256), dim3(256), 0, stream,
                       gw, ow, pw, ws);
    hipLaunchKernelGGL(gru_dec, dim3(NROWS/MT), dim3(512), 0, stream,
                       h, ws, gb, ob, pb, (float*)d_out);
}

// Round 2
// 2568.977 us; speedup vs baseline: 1.2991x; 1.2991x over previous
//
#include <hip/hip_runtime.h>
#include <stdint.h>

// GRU decoder: 65536 independent rows, H=256, T=12, D_OUT=64.
// One block = 64 rows, 4 waves. Weights stream through LDS panels
// (global_load_lds, ring-2, vmcnt-counted). A-operands live in registers.

#define NROWS   65536
#define TSTEPS  12
#define MT      64

typedef _Float16 f16x8 __attribute__((ext_vector_type(8)));
typedef _Float16 f16x4 __attribute__((ext_vector_type(4)));
typedef float    f32x16 __attribute__((ext_vector_type(16)));

// ws layout (f16): Wg_folded[512][256] | W1[256][256] | W2[256][256] | Wp[64][256]
// panel q (q=0..16) = 64 rows x 256 k = 32768 bytes at byte offset q*32768.
#define WG_E   (512*256)
#define W1_E   (256*256)
#define WS_F16_TOTAL (WG_E + 2*W1_E + 64*256)   // 278528 f16 = 557056 B

__global__ void prep_weights(const float* __restrict__ gw,
                             const float* __restrict__ ow,
                             const float* __restrict__ pw,
                             _Float16* __restrict__ ws)
{
    int idx = blockIdx.x*256 + threadIdx.x;
    if (idx < WG_E) {                      // folded gates: gw[:, :256] + gw[:, 256:]
        int j = idx >> 8, k = idx & 255;
        ws[idx] = (_Float16)(gw[j*512 + k] + gw[j*512 + 256 + k]);
    } else if (idx < WG_E + W1_E) {        // W1 = out_w[:, :256]
        int i = idx - WG_E; int r = i >> 8, c = i & 255;
        ws[idx] = (_Float16)ow[r*512 + c];
    } else if (idx < WG_E + 2*W1_E) {      // W2 = out_w[:, 256:]
        int i = idx - WG_E - W1_E; int r = i >> 8, c = i & 255;
        ws[idx] = (_Float16)ow[r*512 + 256 + c];
    } else if (idx < WS_F16_TOTAL) {       // Wp
        int i = idx - WG_E - 2*W1_E;
        ws[idx] = (_Float16)pw[i];
    }
}

__device__ __forceinline__ float sigm(float x)  { return 1.0f/(1.0f+__expf(-x)); }
__device__ __forceinline__ float tanh_(float x) { return 1.0f - 2.0f/(1.0f+__expf(2.0f*x)); }
// tiles/panels: 512B rows; XOR-swizzle bits 4..6 by row&7 (bank-conflict fix)
__device__ __forceinline__ int swzo(int row, int b) { return row*512 + (b ^ ((row&7)<<4)); }

__device__ __forceinline__ void barx() {
    asm volatile("s_waitcnt lgkmcnt(0)" ::: "memory");
    __builtin_amdgcn_s_barrier();
    asm volatile("" ::: "memory");
}
#define WAITV8() asm volatile("s_waitcnt vmcnt(8)" ::: "memory")

// stage one 32KB panel: 8 x global_load_lds(16B) per thread.
// LDS dest is wave-uniform base (HW scatters lane i at +16*i); global source
// carries the inverse XOR swizzle so swizzled ds_reads see linear data.
__device__ __forceinline__ void stage(const uint8_t* W, int pidx, uint8_t* buf,
                                      int wbase, int lane)
{
    const uint8_t* src = W + pidx*32768;
    #pragma unroll
    for (int i = 0; i < 8; ++i) {
        int d  = wbase + i*1024;          // wave-uniform LDS offset
        int dl = d + lane*16;             // where lane's 16B lands
        int s  = dl ^ (((dl>>9)&7)<<4);   // pre-swizzled global offset
        __builtin_amdgcn_global_load_lds(
            (const __attribute__((address_space(1))) uint32_t*)(src + s),
            (__attribute__((address_space(3))) uint32_t*)(buf + d),
            16, 0, 0);
    }
}

__device__ __forceinline__ f16x8 ldfrag(const uint8_t* t, int row, int kb) {
    return *(const f16x8*)(t + swzo(row, kb));
}
__device__ __forceinline__ void ldA(f16x8* A, const uint8_t* tile, int arow, int kg) {
    #pragma unroll
    for (int ks = 0; ks < 16; ++ks) A[ks] = ldfrag(tile, arow, ks*32 + kg*16);
}
__device__ __forceinline__ f32x16 gemmA(const f16x8* A, const uint8_t* pan,
                                        int brow, int kg, f32x16 acc) {
    #pragma unroll
    for (int ks = 0; ks < 16; ++ks) {
        f16x8 b = ldfrag(pan, brow, ks*32 + kg*16);
        acc = __builtin_amdgcn_mfma_f32_32x32x16_f16(A[ks], b, acc, 0, 0, 0);
    }
    return acc;
}

__global__ __launch_bounds__(256, 1)
void gru_dec(const float* __restrict__ h_in, const _Float16* __restrict__ Wf,
             const float* __restrict__ gate_b, const float* __restrict__ out_b,
             const float* __restrict__ proj_b, float* __restrict__ out)
{
    __shared__ __align__(16) uint8_t lds[131072];
    uint8_t* Ht = lds;                 // h tile [64][256] f16, swizzled
    uint8_t* Rt = lds + 32768;         // rh tile
    uint8_t* Wb = lds + 65536;         // 2 x 32KB weight panel ring
    const uint8_t* W = (const uint8_t*)Wf;

    const int tid  = threadIdx.x;
    const int lane = tid & 63;
    const int w    = tid >> 6;          // wave 0..3
    const int mhat = w >> 1, nhat = w & 1;
    const int kg   = lane >> 5;
    const int bl   = lane & 31;
    const int wbase = w*8192;
    const int row0 = blockIdx.x * MT;

    // ---- initial h: f32 global -> f16 swizzled LDS ----
    {
        int r  = tid >> 2;              // 0..63
        int c0 = (tid & 3) * 64;
        const float* src = h_in + (size_t)(row0 + r)*256 + c0;
        #pragma unroll
        for (int i = 0; i < 16; ++i) {
            float4 v = *(const float4*)(src + i*4);
            f16x4 p = { (_Float16)v.x, (_Float16)v.y, (_Float16)v.z, (_Float16)v.w };
            *(f16x4*)(Ht + swzo(r, c0*2 + i*8)) = p;
        }
    }

    float rb[4], zb[4], ob[4];
    #pragma unroll
    for (int k = 0; k < 4; ++k) {
        int c = k*64 + nhat*32 + bl;
        rb[k] = gate_b[c]; zb[k] = gate_b[256 + c]; ob[k] = out_b[c];
    }
    float pb = proj_b[nhat*32 + bl];
    __syncthreads();

    f16x8 hA[16], rA[16];
    ldA(hA, Ht, mhat*32 + bl, kg);

    stage(W, 0, Wb, wbase, lane);       // prologue: panel 0 into buf 0
    int P = 0;

    for (int t = 0; t < TSTEPS; ++t) {
        f32x16 zz[4], oa[4];

        // ---- q=0..3: gate-r panels -> rh tile ----
        #pragma unroll
        for (int k = 0; k < 4; ++k) {
            stage(W, k+1, Wb + ((P+1)&1)*32768, wbase, lane);
            WAITV8(); barx();
            const uint8_t* pan = Wb + (P&1)*32768;
            f32x16 acc = {};
            acc = gemmA(hA, pan, nhat*32 + bl, kg, acc);
            #pragma unroll
            for (int e = 0; e < 16; ++e) {
                int row = mhat*32 + (e&3) + 8*(e>>2) + 4*kg;
                int cb  = (k*64 + nhat*32 + bl)*2;
                float hc = (float)*(const _Float16*)(Ht + swzo(row, cb));
                float r  = sigm(acc[e] + rb[k]);
                *(_Float16*)(Rt + swzo(row, cb)) = (_Float16)(r*hc);
            }
            barx(); ++P;
        }
        // ---- q=4..7: gate-z panels -> z regs ----
        #pragma unroll
        for (int k = 0; k < 4; ++k) {
            stage(W, 5+k, Wb + ((P+1)&1)*32768, wbase, lane);
            WAITV8(); barx();
            if (k == 0) ldA(rA, Rt, mhat*32 + bl, kg);   // rh complete
            const uint8_t* pan = Wb + (P&1)*32768;
            f32x16 acc = {};
            acc = gemmA(hA, pan, nhat*32 + bl, kg, acc);
            #pragma unroll
            for (int e = 0; e < 16; ++e) zz[k][e] = sigm(acc[e] + zb[k]);
            barx(); ++P;
        }
        // ---- q=8..11: W1 panels (o partial, held in regs) ----
        #pragma unroll
        for (int k = 0; k < 4; ++k) {
            stage(W, 9+k, Wb + ((P+1)&1)*32768, wbase, lane);
            WAITV8(); barx();
            const uint8_t* pan = Wb + (P&1)*32768;
            f32x16 acc = {};
            oa[k] = gemmA(hA, pan, nhat*32 + bl, kg, acc);
            barx(); ++P;
        }
        // ---- q=12..15: W2 panels + in-place h update ----
        #pragma unroll
        for (int k = 0; k < 4; ++k) {
            stage(W, 13+k, Wb + ((P+1)&1)*32768, wbase, lane);   // k=3 -> panel 16
            WAITV8(); barx();
            const uint8_t* pan = Wb + (P&1)*32768;
            oa[k] = gemmA(rA, pan, nhat*32 + bl, kg, oa[k]);
            #pragma unroll
            for (int e = 0; e < 16; ++e) {
                int row = mhat*32 + (e&3) + 8*(e>>2) + 4*kg;
                int cb  = (k*64 + nhat*32 + bl)*2;
                float hold = (float)*(const _Float16*)(Ht + swzo(row, cb));
                float hn   = tanh_(oa[k][e] + ob[k]);
                float z    = zz[k][e];
                *(_Float16*)(Ht + swzo(row, cb)) = (_Float16)(z*hold + (1.0f - z)*hn);
            }
            barx(); ++P;
        }
        // ---- q=16: proj panel -> out ----
        {
            stage(W, 0, Wb + ((P+1)&1)*32768, wbase, lane);      // next step's r0
            WAITV8(); barx();
            ldA(hA, Ht, mhat*32 + bl, kg);                        // h_new
            const uint8_t* pan = Wb + (P&1)*32768;
            f32x16 acc = {};
            acc = gemmA(hA, pan, nhat*32 + bl, kg, acc);
            #pragma unroll
            for (int e = 0; e < 16; ++e) {
                int row = mhat*32 + (e&3) + 8*(e>>2) + 4*kg;
                out[((size_t)(row0 + row)*TSTEPS + t)*64 + nhat*32 + bl] = acc[e] + pb;
            }
            barx(); ++P;
        }
    }
}

extern "C" void kernel_launch(void* const* d_in, const int* in_sizes, int n_in,
                              void* d_out, int out_size, void* d_ws, size_t ws_size,
                              hipStream_t stream) {
    // inputs: 0:x(=12) 1:h 2:gate_w 3:gate_b 4:out_w 5:out_b 6:proj_w 7:proj_b
    const float* h  = (const float*)d_in[1];
    const float* gw = (const float*)d_in[2];
    const float* gb = (const float*)d_in[3];
    const float* ow = (const float*)d_in[4];
    const float* ob = (const float*)d_in[5];
    const float* pw = (const float*)d_in[6];
    const float* pb = (const float*)d_in[7];
    if (ws_size < (size_t)WS_F16_TOTAL * sizeof(_Float16)) return;
    _Float16* ws = (_Float16*)d_ws;

    hipLaunchKernelGGL(prep_weights, dim3((WS_F16_TOTAL + 255)/256), dim3(256), 0, stream,
                       gw, ow, pw, ws);
    hipLaunchKernelGGL(gru_dec, dim3(NROWS/MT), dim3(256), 0, stream,
                       h, ws, gb, ob, pb, (float*)d_out);
}

// Round 4
// 2013.199 us; speedup vs baseline: 1.6578x; 1.2761x over previous
//
#include <hip/hip_runtime.h>
#include <stdint.h>

// GRU decoder: 65536 rows, H=256, T=12, D_OUT=64.
// 512 blocks x 512 threads: two 64-row groups per block (2 waves/SIMD).
// Weights stream through a ring-3 of 32KB LDS panels (global_load_lds,
// vmcnt(4)-counted, staged 2 phases ahead). A-operands live in registers.
// LDS layout "interleaved-16B": (row,b) -> (row>>3)*4096 + (b>>4)*128 +
// (row&7)*16 + (b&15)  -- bank-balanced, all offsets compile-time imms.

#define NROWS   65536
#define TSTEPS  12

typedef _Float16 f16x8  __attribute__((ext_vector_type(8)));
typedef _Float16 f16x4  __attribute__((ext_vector_type(4)));
typedef _Float16 f16x16v __attribute__((ext_vector_type(16)));
typedef float    f32x16 __attribute__((ext_vector_type(16)));

// ws layout (f16): Wg_folded[512][256] | W1[256][256] | W2[256][256] | Wp[64][256]
// panel q = 64 rows x 256 k = 32KB. panels: 0-3 gate-r, 4-7 gate-z, 8-11 W1,
// 12-15 W2, 16 Wp.
#define WG_E   (512*256)
#define W1_E   (256*256)
#define WS_F16_TOTAL (WG_E + 2*W1_E + 64*256)

__global__ void prep_weights(const float* __restrict__ gw,
                             const float* __restrict__ ow,
                             const float* __restrict__ pw,
                             _Float16* __restrict__ ws)
{
    int idx = blockIdx.x*256 + threadIdx.x;
    if (idx < WG_E) {                      // folded gates
        int j = idx >> 8, k = idx & 255;
        ws[idx] = (_Float16)(gw[j*512 + k] + gw[j*512 + 256 + k]);
    } else if (idx < WG_E + W1_E) {        // W1 = out_w[:, :256]
        int i = idx - WG_E; int r = i >> 8, c = i & 255;
        ws[idx] = (_Float16)ow[r*512 + c];
    } else if (idx < WG_E + 2*W1_E) {      // W2 = out_w[:, 256:]
        int i = idx - WG_E - W1_E; int r = i >> 8, c = i & 255;
        ws[idx] = (_Float16)ow[r*512 + 256 + c];
    } else if (idx < WS_F16_TOTAL) {       // Wp
        ws[idx] = (_Float16)pw[idx - WG_E - 2*W1_E];
    }
}

__device__ __forceinline__ float sigm(float x)  { return 1.0f/(1.0f+__expf(-x)); }
__device__ __forceinline__ float tanh_(float x) { return 1.0f - 2.0f/(1.0f+__expf(2.0f*x)); }

// stage one 32KB panel cooperatively (8 waves x 4 x gll16). LDS dest linear;
// global source carries the inverse layout permutation.
__device__ __forceinline__ void stage(const uint8_t* __restrict__ Wp,
                                      uint8_t* slot, int w, int lane)
{
    #pragma unroll
    for (int i = 0; i < 4; ++i) {
        int d  = w*4096 + i*1024;              // wave-uniform LDS offset
        int dl = d + lane*16;
        int row = ((dl>>12)<<3) | ((dl>>4)&7);
        int s   = row*512 + ((dl>>7)&31)*16;   // linear (row,b) source
        __builtin_amdgcn_global_load_lds(
            (const __attribute__((address_space(1))) uint32_t*)(Wp + s),
            (__attribute__((address_space(3))) uint32_t*)(slot + d),
            16, 0, 0);
    }
}

__device__ __forceinline__ void ldA(f16x8* A, const uint8_t* base) {
    #pragma unroll
    for (int ks = 0; ks < 16; ++ks) A[ks] = *(const f16x8*)(base + ks*256);
}
__device__ __forceinline__ f32x16 gemmAcc(const f16x8* A, const uint8_t* pb_,
                                          f32x16 acc) {
    #pragma unroll
    for (int ks = 0; ks < 16; ++ks) {
        f16x8 b = *(const f16x8*)(pb_ + ks*256);
        acc = __builtin_amdgcn_mfma_f32_32x32x16_f16(A[ks], b, acc, 0, 0, 0);
    }
    return acc;
}

// phase: wait compute-slot loads -> barrier -> stage 2-ahead -> compute
#define PH(SP, ...) do {                                                    \
    asm volatile("s_waitcnt vmcnt(4)" ::: "memory");                        \
    asm volatile("s_waitcnt lgkmcnt(0)" ::: "memory");                      \
    __builtin_amdgcn_s_barrier();                                           \
    { int sS = sC + 2; if (sS >= 3) sS -= 3;                                \
      stage(W + (size_t)(SP)*32768, Wb + sS*32768, w, lane); }              \
    { const uint8_t* pan = Wb + sC*32768; __VA_ARGS__; }                    \
    sC = (sC == 2) ? 0 : sC + 1;                                            \
} while (0)

__global__ __launch_bounds__(512, 2)
void gru_dec(const float* __restrict__ h_in, const _Float16* __restrict__ Wf,
             const float* __restrict__ gate_b, const float* __restrict__ out_b,
             const float* __restrict__ proj_b, float* __restrict__ out)
{
    __shared__ __align__(16) uint8_t lds[163840];
    uint8_t* Wb = lds + 65536;                 // 3 x 32KB panel ring
    const uint8_t* W = (const uint8_t*)Wf;

    const int tid  = threadIdx.x;
    const int lane = tid & 63;
    const int w    = tid >> 6;                 // 0..7
    const int g    = w >> 2;                   // row group 0/1
    const int wl   = w & 3;
    const int mhat = wl >> 1, nhat = wl & 1;
    const int kg   = lane >> 5, bl = lane & 31;
    uint8_t* Ht = lds + g*32768;               // [64 rows][256 f16], interleaved
    const int row0 = blockIdx.x*128 + g*64;

    // ---- initial h: 512 threads cover 128 rows x 256 cols, f32 -> f16 ----
    {
        int r  = tid >> 2;                     // 0..127
        int lr = r & 63;
        uint8_t* base = lds + (r>>6)*32768 + (lr>>3)*4096 + (lr&7)*16;
        const float* src = h_in + (size_t)(blockIdx.x*128 + r)*256 + (tid&3)*64;
        #pragma unroll
        for (int i = 0; i < 16; ++i) {
            float4 v = *(const float4*)(src + i*4);
            f16x4 p = {(_Float16)v.x,(_Float16)v.y,(_Float16)v.z,(_Float16)v.w};
            int c = (tid&3)*64 + i*4;
            *(f16x4*)(base + (c>>3)*128 + (c&7)*2) = p;
        }
    }

    float rb[4], zb[4], ob2[4];
    #pragma unroll
    for (int k = 0; k < 4; ++k) {
        int c = k*64 + nhat*32 + bl;
        rb[k] = gate_b[c]; zb[k] = gate_b[256 + c]; ob2[k] = out_b[c];
    }
    const float pb = proj_b[nhat*32 + bl];
    __syncthreads();

    // per-lane fragment address bases (all subsequent offsets are imms)
    const int aoff = (mhat*4 + (bl>>3))*4096 + (bl&7)*16 + kg*128;   // A row=mhat*32+bl
    const int boff = (nhat*4 + (bl>>3))*4096 + (bl&7)*16 + kg*128;   // B row=nhat*32+bl
    const int eoff = mhat*16384 + kg*64 + (nhat*4 + (bl>>3))*128 + (bl&7)*2;

    f16x8 A[16];
    ldA(A, Ht + aoff);                         // A = h

    stage(W + 8*32768, Wb,         w, lane);   // prologue: W1 panels 8,9
    stage(W + 9*32768, Wb + 32768, w, lane);
    int sC = 0;

    for (int t = 0; t < TSTEPS; ++t) {
        f32x16 oa0, oa1, oa2, oa3;
        f16x16v zz[4], hold[4];

        // ---- W1 (panels 8..11): oa[k] = h @ W1_k^T ----
        PH(10, { f32x16 a_ = {}; oa0 = gemmAcc(A, pan + boff, a_); });
        PH(11, { f32x16 a_ = {}; oa1 = gemmAcc(A, pan + boff, a_); });
        PH(4,  { f32x16 a_ = {}; oa2 = gemmAcc(A, pan + boff, a_); });
        PH(5,  { f32x16 a_ = {}; oa3 = gemmAcc(A, pan + boff, a_); });

        // ---- z gates (panels 4..7): zz[k] f16 in regs ----
#define ZPH(SPAN, K)                                                          \
        PH(SPAN, { f32x16 acc = {}; acc = gemmAcc(A, pan + boff, acc);        \
            _Pragma("unroll")                                                 \
            for (int e = 0; e < 16; ++e)                                      \
                zz[K][e] = (_Float16)sigm(acc[e] + zb[K]); })
        ZPH(6, 0); ZPH(7, 1); ZPH(0, 2); ZPH(1, 3);
#undef ZPH

        // ---- r gates (panels 0..3): hold h_old in regs, rh overwrites Ht ----
#define RPH(SPAN, K)                                                          \
        PH(SPAN, { f32x16 acc = {}; acc = gemmAcc(A, pan + boff, acc);        \
            _Pragma("unroll")                                                 \
            for (int e = 0; e < 16; ++e) {                                    \
                uint8_t* p = Ht + eoff + (K)*1024 + (e>>2)*4096 + (e&3)*16;   \
                float hc = (float)*(const _Float16*)p;                        \
                hold[K][e] = (_Float16)hc;                                    \
                *(_Float16*)p = (_Float16)(sigm(acc[e] + rb[K]) * hc);        \
            } })
        RPH(2, 0); RPH(3, 1); RPH(12, 2); RPH(13, 3);
#undef RPH

        // ---- W2 (panels 12..15): oa[k] += rh @ W2_k^T; write h_new ----
        PH(14, {
            ldA(A, Ht + aoff);                                  // A = rh
            asm volatile("s_waitcnt lgkmcnt(0)" ::: "memory");
            __builtin_amdgcn_s_barrier();                       // all rA loaded
            oa0 = gemmAcc(A, pan + boff, oa0);
            _Pragma("unroll")
            for (int e = 0; e < 16; ++e) {
                float hn = tanh_(oa0[e] + ob2[0]);
                float z  = (float)zz[0][e];
                uint8_t* p = Ht + eoff + 0*1024 + (e>>2)*4096 + (e&3)*16;
                *(_Float16*)p = (_Float16)(z*(float)hold[0][e] + (1.0f - z)*hn);
            } });
#define W2PH(SPAN, K, OA)                                                     \
        PH(SPAN, { OA = gemmAcc(A, pan + boff, OA);                           \
            _Pragma("unroll")                                                 \
            for (int e = 0; e < 16; ++e) {                                    \
                float hn = tanh_(OA[e] + ob2[K]);                             \
                float z  = (float)zz[K][e];                                   \
                uint8_t* p = Ht + eoff + (K)*1024 + (e>>2)*4096 + (e&3)*16;   \
                *(_Float16*)p = (_Float16)(z*(float)hold[K][e] + (1.0f - z)*hn); \
            } })
        W2PH(15, 1, oa1); W2PH(16, 2, oa2); W2PH(8, 3, oa3);
#undef W2PH

        // ---- proj (panel 16): out_t = h_new @ Wp^T + pb; A <- h_new ----
        PH(9, {
            ldA(A, Ht + aoff);                                  // A = h_new
            f32x16 acc = {}; acc = gemmAcc(A, pan + boff, acc);
            _Pragma("unroll")
            for (int e = 0; e < 16; ++e) {
                int row = mhat*32 + (e&3) + 8*(e>>2) + 4*kg;
                out[((size_t)(row0 + row)*TSTEPS + t)*64 + nhat*32 + bl] = acc[e] + pb;
            } });
    }
}

extern "C" void kernel_launch(void* const* d_in, const int* in_sizes, int n_in,
                              void* d_out, int out_size, void* d_ws, size_t ws_size,
                              hipStream_t stream) {
    // inputs: 0:x(=12) 1:h 2:gate_w 3:gate_b 4:out_w 5:out_b 6:proj_w 7:proj_b
    const float* h  = (const float*)d_in[1];
    const float* gw = (const float*)d_in[2];
    const float* gb = (const float*)d_in[3];
    const float* ow = (const float*)d_in[4];
    const float* ob = (const float*)d_in[5];
    const float* pw = (const float*)d_in[6];
    const float* pb = (const float*)d_in[7];
    if (ws_size < (size_t)WS_F16_TOTAL * sizeof(_Float16)) return;
    _Float16* ws = (_Float16*)d_ws;

    hipLaunchKernelGGL(prep_weights, dim3((WS_F16_TOTAL + 255)/256), dim3(256), 0, stream,
                       gw, ow, pw, ws);
    hipLaunchKernelGGL(gru_dec, dim3(NROWS/128), dim3(512), 0, stream,
                       h, ws, gb, ob, pb, (float*)d_out);
}

// Round 5
// 1809.233 us; speedup vs baseline: 1.8447x; 1.1127x over previous
//
#include <hip/hip_runtime.h>
#include <stdint.h>

// GRU decoder: 65536 rows, H=256, T=12, D_OUT=64.
// 512 blocks x 512 threads (8 waves; two 64-row groups; 2 waves/SIMD).
// Weights stream through a ring-3 of 32KB LDS panels (global_load_lds,
// vmcnt(4), staged 2 phases ahead). Phase order per step:
//   W1(4) -> z(4) -> r(4) -> W2(4)+combine -> proj
// A-operands in regs (h for W1/z/r, rh for W2, h_new for proj).
// LDS layout, chunk-XOR: L(row,b) = (row>>3)*4096 + (b>>4)*128
//   + (((row&7) ^ ((b>>4)&7))<<4) + (b&15)   -- elementwise conflict-free.

#define NROWS   65536
#define TSTEPS  12

typedef _Float16 f16x8  __attribute__((ext_vector_type(8)));
typedef _Float16 f16x4  __attribute__((ext_vector_type(4)));
typedef _Float16 f16x16v __attribute__((ext_vector_type(16)));
typedef float    f32x16 __attribute__((ext_vector_type(16)));

// ws layout (f16): Wg_folded[512][256] | W1[256][256] | W2[256][256] | Wp[64][256]
// panel q = 64 rows x 256 k = 32KB: 0-3 gate-r, 4-7 gate-z, 8-11 W1, 12-15 W2, 16 Wp
#define WG_E   (512*256)
#define W1_E   (256*256)
#define WS_F16_TOTAL (WG_E + 2*W1_E + 64*256)

__global__ void prep_weights(const float* __restrict__ gw,
                             const float* __restrict__ ow,
                             const float* __restrict__ pw,
                             _Float16* __restrict__ ws)
{
    int idx = blockIdx.x*256 + threadIdx.x;
    if (idx < WG_E) {                      // folded gates
        int j = idx >> 8, k = idx & 255;
        ws[idx] = (_Float16)(gw[j*512 + k] + gw[j*512 + 256 + k]);
    } else if (idx < WG_E + W1_E) {        // W1 = out_w[:, :256]
        int i = idx - WG_E; int r = i >> 8, c = i & 255;
        ws[idx] = (_Float16)ow[r*512 + c];
    } else if (idx < WG_E + 2*W1_E) {      // W2 = out_w[:, 256:]
        int i = idx - WG_E - W1_E; int r = i >> 8, c = i & 255;
        ws[idx] = (_Float16)ow[r*512 + 256 + c];
    } else if (idx < WS_F16_TOTAL) {       // Wp
        ws[idx] = (_Float16)pw[idx - WG_E - 2*W1_E];
    }
}

__device__ __forceinline__ float sigm(float x)  { return 1.0f/(1.0f+__expf(-x)); }
__device__ __forceinline__ float tanh_(float x) { return 1.0f - 2.0f/(1.0f+__expf(2.0f*x)); }

// stage one 32KB panel cooperatively (8 waves x 4 gll16). LDS dest linear;
// global source carries the inverse chunk-XOR permutation.
__device__ __forceinline__ void stage(const uint8_t* __restrict__ Wp,
                                      uint8_t* slot_, int w, int lane)
{
    #pragma unroll
    for (int i = 0; i < 4; ++i) {
        int d  = w*4096 + i*1024;              // wave-uniform LDS offset
        int dl = d + lane*16;
        int chunk = (dl>>7)&31;
        int sl    = (dl>>4)&7;
        int row   = ((dl>>12)<<3) | (sl ^ (chunk&7));
        int s     = row*512 + chunk*16;
        __builtin_amdgcn_global_load_lds(
            (const __attribute__((address_space(1))) uint32_t*)(Wp + s),
            (__attribute__((address_space(3))) uint32_t*)(slot_ + d),
            16, 0, 0);
    }
}

struct Bases { const uint8_t* p[4]; };

__device__ __forceinline__ Bases mkbases(const uint8_t* base, int off, int u2) {
    Bases b;
    #pragma unroll
    for (int j = 0; j < 4; ++j) b.p[j] = base + off + (u2 ^ (j<<5));
    return b;
}
__device__ __forceinline__ void ldA(f16x8* A, const Bases& aB) {
    #pragma unroll
    for (int ks = 0; ks < 16; ++ks)
        A[ks] = *(const f16x8*)(aB.p[ks&3] + ks*256);
}
__device__ __forceinline__ f32x16 gemm4(const Bases& bb, const f16x8* A, f32x16 acc) {
    #pragma unroll
    for (int ks = 0; ks < 16; ++ks) {
        f16x8 b = *(const f16x8*)(bb.p[ks&3] + ks*256);
        acc = __builtin_amdgcn_mfma_f32_32x32x16_f16(A[ks], b, acc, 0, 0, 0);
    }
    return acc;
}

// phase: wait compute-slot loads -> barrier -> stage 2-ahead -> compute
#define PH(SP, ...) do {                                                    \
    asm volatile("s_waitcnt vmcnt(4)" ::: "memory");                        \
    asm volatile("s_waitcnt lgkmcnt(0)" ::: "memory");                      \
    __builtin_amdgcn_s_barrier();                                           \
    asm volatile("" ::: "memory");                                          \
    { int sS = sC + 2; if (sS >= 3) sS -= 3;                                \
      stage(W + (size_t)(SP)*32768, Wb + sS*32768, w, lane); }              \
    { const uint8_t* pan = Wb + sC*32768;                                   \
      Bases bb = mkbases(pan, Bc, u2); (void)bb; __VA_ARGS__; }             \
    sC = (sC == 2) ? 0 : sC + 1;                                            \
} while (0)

__global__ __launch_bounds__(512, 2)
void gru_dec(const float* __restrict__ h_in, const _Float16* __restrict__ Wf,
             const float* __restrict__ gate_b, const float* __restrict__ out_b,
             const float* __restrict__ proj_b, float* __restrict__ out)
{
    __shared__ __align__(16) uint8_t lds[163840];
    uint8_t* Wb = lds + 65536;                 // 3 x 32KB panel ring
    const uint8_t* W = (const uint8_t*)Wf;

    const int tid  = threadIdx.x;
    const int lane = tid & 63;
    const int w    = tid >> 6;                 // 0..7
    const int g    = w >> 2;                   // row group 0/1
    const int wl   = w & 3;
    const int mhat = wl >> 1, nhat = wl & 1;
    const int kg   = lane >> 5, bl = lane & 31;
    uint8_t* Ht = lds + g*32768;               // [64 rows][256 f16], chunk-XOR
    const int row0 = blockIdx.x*128 + g*64;

    // ---- initial h: 512 threads cover 128 rows x 256 cols, f32 -> f16 ----
    {
        int r  = tid >> 2;                     // 0..127
        int lr = r & 63;
        uint8_t* gb2 = lds + (r>>6)*32768 + (lr>>3)*4096;
        int sl7 = lr & 7;
        const float* src = h_in + (size_t)(blockIdx.x*128 + r)*256 + (tid&3)*64;
        #pragma unroll
        for (int i = 0; i < 16; ++i) {
            float4 v = *(const float4*)(src + i*4);
            f16x4 p = {(_Float16)v.x,(_Float16)v.y,(_Float16)v.z,(_Float16)v.w};
            int c = (tid&3)*64 + i*4;
            int chunk = c>>3;
            *(f16x4*)(gb2 + chunk*128 + ((sl7 ^ (chunk&7))<<4) + (c&7)*2) = p;
        }
    }

    float rb[4], zb[4], ob2[4];
    #pragma unroll
    for (int k = 0; k < 4; ++k) {
        int c = k*64 + nhat*32 + bl;
        rb[k] = gate_b[c]; zb[k] = gate_b[256 + c]; ob2[k] = out_b[c];
    }
    const float pb = proj_b[nhat*32 + bl];

    // per-lane addressing constants
    const int u2 = ((bl&7) ^ kg) << 4;
    const int Bc = (nhat*4 + (bl>>3))*4096 + kg*128;     // B page base in panel
    const int Ac = (mhat*4 + (bl>>3))*4096 + kg*128;     // A page base in Ht
    const int q  = nhat*4 + (bl>>3);
    const int m16 = ((kg<<2) ^ q) << 4;
    const int E0 = mhat*16384 + q*128 + (bl&7)*2;
    uint8_t* X[4];
    #pragma unroll
    for (int j = 0; j < 4; ++j) X[j] = Ht + E0 + ((j*16) ^ m16);
    const Bases aB = mkbases(Ht, Ac, u2);

    __syncthreads();

    f16x8 A[16];
    ldA(A, aB);                                // A = h

    stage(W + 8*32768, Wb,         w, lane);   // prologue: panels 8,9
    stage(W + 9*32768, Wb + 32768, w, lane);
    int sC = 0;

    for (int t = 0; t < TSTEPS; ++t) {
        f32x16 oa0, oa1, oa2, oa3;
        f16x16v zz[4], hold[4];

        // ---- W1 (panels 8..11): oa_k = h @ W1_k^T ----
        PH(10, { f32x16 a_ = {}; oa0 = gemm4(bb, A, a_); });
        PH(11, { f32x16 a_ = {}; oa1 = gemm4(bb, A, a_); });
        PH(4,  { f32x16 a_ = {}; oa2 = gemm4(bb, A, a_); });
        PH(5,  { f32x16 a_ = {}; oa3 = gemm4(bb, A, a_); });

        // ---- z gates (panels 4..7): zz_k f16 in regs ----
#define ZPH(SPAN, K)                                                          \
        PH(SPAN, { f32x16 acc = {}; acc = gemm4(bb, A, acc);                  \
            _Pragma("unroll")                                                 \
            for (int e = 0; e < 16; ++e)                                      \
                zz[K][e] = (_Float16)sigm(acc[e] + zb[K]); })
        ZPH(6, 0); ZPH(7, 1); ZPH(0, 2); ZPH(1, 3);
#undef ZPH

        // ---- r gates (panels 0..3): capture h_old, write rh over Ht band k ----
#define RPH(SPAN, K)                                                          \
        PH(SPAN, { f32x16 acc = {}; acc = gemm4(bb, A, acc);                  \
            _Pragma("unroll")                                                 \
            for (int e = 0; e < 16; ++e) {                                    \
                uint8_t* p = X[e&3] + (K)*1024 + (e>>2)*4096;                 \
                float hc = (float)*(const _Float16*)p;                        \
                hold[K][e] = (_Float16)hc;                                    \
                *(_Float16*)p = (_Float16)(sigm(acc[e] + rb[K]) * hc);        \
            } })
        RPH(2, 0); RPH(3, 1); RPH(12, 2); RPH(13, 3);
#undef RPH

        // ---- W2 (panels 12..15): oa_k += rh @ W2_k^T; combine; write h_new ----
        PH(14, {
            ldA(A, aB);                                     // A = rh (all bands)
            asm volatile("s_waitcnt lgkmcnt(0)" ::: "memory");
            __builtin_amdgcn_s_barrier();                   // all waves loaded rh
            asm volatile("" ::: "memory");
            oa0 = gemm4(bb, A, oa0);
            _Pragma("unroll")
            for (int e = 0; e < 16; ++e) {
                float u = tanh_(oa0[e] + ob2[0]);
                float z = (float)zz[0][e];
                uint8_t* p = X[e&3] + 0*1024 + (e>>2)*4096;
                *(_Float16*)p = (_Float16)(z*(float)hold[0][e] + (1.0f - z)*u);
            } });
#define W2PH(SPAN, K, OA)                                                     \
        PH(SPAN, { OA = gemm4(bb, A, OA);                                     \
            _Pragma("unroll")                                                 \
            for (int e = 0; e < 16; ++e) {                                    \
                float u = tanh_(OA[e] + ob2[K]);                              \
                float z = (float)zz[K][e];                                    \
                uint8_t* p = X[e&3] + (K)*1024 + (e>>2)*4096;                 \
                *(_Float16*)p = (_Float16)(z*(float)hold[K][e] + (1.0f - z)*u); \
            } })
        W2PH(15, 1, oa1); W2PH(16, 2, oa2); W2PH(8, 3, oa3);
#undef W2PH

        // ---- proj (panel 16): A <- h_new; out_t = h_new @ Wp^T + pb ----
        PH(9, {
            ldA(A, aB);                                     // A = h_new
            f32x16 acc = {}; acc = gemm4(bb, A, acc);
            _Pragma("unroll")
            for (int e = 0; e < 16; ++e) {
                int row = mhat*32 + (e&3) + 8*(e>>2) + 4*kg;
                __builtin_nontemporal_store(acc[e] + pb,
                    &out[((size_t)(row0 + row)*TSTEPS + t)*64 + nhat*32 + bl]);
            } });
    }
}

extern "C" void kernel_launch(void* const* d_in, const int* in_sizes, int n_in,
                              void* d_out, int out_size, void* d_ws, size_t ws_size,
                              hipStream_t stream) {
    // inputs: 0:x(=12) 1:h 2:gate_w 3:gate_b 4:out_w 5:out_b 6:proj_w 7:proj_b
    const float* h  = (const float*)d_in[1];
    const float* gw = (const float*)d_in[2];
    const float* gb = (const float*)d_in[3];
    const float* ow = (const float*)d_in[4];
    const float* ob = (const float*)d_in[5];
    const float* pw = (const float*)d_in[6];
    const float* pb = (const float*)d_in[7];
    if (ws_size < (size_t)WS_F16_TOTAL * sizeof(_Float16)) return;
    _Float16* ws = (_Float16*)d_ws;

    hipLaunchKernelGGL(prep_weights, dim3((WS_F16_TOTAL + 255)/256), dim3(256), 0, stream,
                       gw, ow, pw, ws);
    hipLaunchKernelGGL(gru_dec, dim3(NROWS/128), dim3(512), 0, stream,
                       h, ws, gb, ob, pb, (float*)d_out);
}